// Round 9
// baseline (2200.580 us; speedup 1.0000x reference)
//
#include <hip/hip_runtime.h>

// ---------- constants ----------
#define B_   64
#define P_   196
#define ENC_ 512
#define ATT_ 256
#define DEC_ 256
#define EMB_ 256
#define V_   10000
#define T_   44
#define G4_  1024          // 4*DEC
#define XW_  768           // EMB+ENC (W_ih inner dim)
#define A1N_ 26624         // att1h per-b u32 count: 128 a2 * 208 p

using short8 = __attribute__((ext_vector_type(8))) short;
using half8  = __attribute__((ext_vector_type(8))) _Float16;
using f32x4  = __attribute__((ext_vector_type(4))) float;
typedef _Float16 f16x2 __attribute__((ext_vector_type(2)));

__device__ __forceinline__ unsigned short f2bf(float f) {
    unsigned int u = __float_as_uint(f);
    unsigned int r = (u + 0x7fffu + ((u >> 16) & 1u)) >> 16;
    return (unsigned short)r;
}

__device__ __forceinline__ unsigned int pkh2(float a, float b) {
    f16x2 t; t.x = (_Float16)a; t.y = (_Float16)b;
    return __builtin_bit_cast(unsigned int, t);
}

// fp16x2 dot with fp32 accumulate (single V_DOT2_F32_F16 where available)
__device__ __forceinline__ float fdot2f(float wbits, f16x2 xv, float acc) {
    f16x2 wv = __builtin_bit_cast(f16x2, wbits);
#if __has_builtin(__builtin_amdgcn_fdot2)
    return __builtin_amdgcn_fdot2(wv, xv, acc, false);
#else
    acc = fmaf((float)wv.x, (float)xv.x, acc);
    acc = fmaf((float)wv.y, (float)xv.y, acc);
    return acc;
#endif
}
__device__ __forceinline__ float fdot2u(unsigned int wbits, f16x2 xv, float acc) {
    f16x2 wv = __builtin_bit_cast(f16x2, wbits);
#if __has_builtin(__builtin_amdgcn_fdot2)
    return __builtin_amdgcn_fdot2(wv, xv, acc, false);
#else
    acc = fmaf((float)wv.x, (float)xv.x, acc);
    acc = fmaf((float)wv.y, (float)xv.y, acc);
    return acc;
#endif
}

// raw barrier: drains LDS ops only; global loads stay in flight (T4).
__device__ __forceinline__ void bar() {
    asm volatile("s_waitcnt lgkmcnt(0)" ::: "memory");
    __builtin_amdgcn_s_barrier();
    asm volatile("" ::: "memory");
}

// ---------- generic 32x32 transpose: dst[k*N + n] = src[n*stride + off + k] ----------
__global__ void k_transpose(const float* __restrict__ src, float* __restrict__ dst,
                            int N, int stride, int off) {
    __shared__ float t[32][33];
    int k0 = blockIdx.x * 32, n0 = blockIdx.y * 32;
    int tx = threadIdx.x & 31, ty = threadIdx.x >> 5;
    for (int r = ty; r < 32; r += 8)
        t[r][tx] = src[(size_t)(n0 + r) * stride + off + k0 + tx];
    __syncthreads();
    for (int r = ty; r < 32; r += 8)
        dst[(size_t)(k0 + r) * N + n0 + tx] = t[tx][r];
}

// ---------- pack W_dec_att [a][d] -> WdaP4[d4*256+a] = {W[a][4d4..4d4+3]} ----------
__global__ __launch_bounds__(256) void k_packWda(const float* __restrict__ Wda,
                                                 float4* __restrict__ WdaP4) {
    int d4 = blockIdx.x, a = threadIdx.x;
    float4 v;
    v.x = Wda[(size_t)a * DEC_ + 4 * d4 + 0];
    v.y = Wda[(size_t)a * DEC_ + 4 * d4 + 1];
    v.z = Wda[(size_t)a * DEC_ + 4 * d4 + 2];
    v.w = Wda[(size_t)a * DEC_ + 4 * d4 + 3];
    WdaP4[(size_t)d4 * 256 + a] = v;
}

// ---------- pack gate weights fp16: Wg4[k2*256+d] = 4 gates x half2(k=2k2,2k2+1) ----------
// k<512 -> W_ih[:, k] (ctx part); k>=512 -> W_hh[:, k-512] (h part). grid 384 x 256.
__global__ __launch_bounds__(256) void k_packWg(const float* __restrict__ Wih,
        const float* __restrict__ Whh, float4* __restrict__ Wg4) {
    int k2 = blockIdx.x, d = threadIdx.x;
    int k = 2 * k2;
    unsigned int o[4];
#pragma unroll
    for (int g = 0; g < 4; ++g) {
        int row = g * 256 + d;
        float a0, a1;
        if (k < ENC_) {
            a0 = Wih[(size_t)row * XW_ + k];
            a1 = Wih[(size_t)row * XW_ + k + 1];
        } else {
            a0 = Whh[(size_t)row * DEC_ + k - ENC_];
            a1 = Whh[(size_t)row * DEC_ + k - ENC_ + 1];
        }
        o[g] = pkh2(a0, a1);
    }
    float4 v;
    v.x = __builtin_bit_cast(float, o[0]);
    v.y = __builtin_bit_cast(float, o[1]);
    v.z = __builtin_bit_cast(float, o[2]);
    v.w = __builtin_bit_cast(float, o[3]);
    Wg4[(size_t)k2 * 256 + d] = v;
}

// ---------- pack enc fp16: encPh[(b*49+p4)*512+e] = uint2{h2(p=4p4,4p4+1), h2(4p4+2,4p4+3)} ----------
// grid: (64 b, 7), each y handles 7 p4 values
__global__ __launch_bounds__(256) void k_packenc(const float* __restrict__ enc,
                                                 uint2* __restrict__ encPh) {
    int b = blockIdx.x, p4b = blockIdx.y * 7;
    for (int p4 = p4b; p4 < p4b + 7; ++p4) {
        for (int e = threadIdx.x; e < ENC_; e += 256) {
            float a0 = enc[((size_t)b * P_ + 4 * p4 + 0) * ENC_ + e];
            float a1 = enc[((size_t)b * P_ + 4 * p4 + 1) * ENC_ + e];
            float a2 = enc[((size_t)b * P_ + 4 * p4 + 2) * ENC_ + e];
            float a3 = enc[((size_t)b * P_ + 4 * p4 + 3) * ENC_ + e];
            uint2 v; v.x = pkh2(a0, a1); v.y = pkh2(a2, a3);
            encPh[((size_t)b * 49 + p4) * ENC_ + e] = v;
        }
    }
}

// ---------- fp32 -> bf16 convert ----------
__global__ void k_cvt(const float* __restrict__ src, unsigned short* __restrict__ dst, int n) {
    int i = blockIdx.x * 256 + threadIdx.x;
    if (i < n) dst[i] = f2bf(src[i]);
}

// ---------- h0/c0 from mean-pooled encoder ----------
__global__ __launch_bounds__(256) void k_init_state(
        const float* __restrict__ enc,
        const float* __restrict__ W_init_h, const float* __restrict__ b_init_h,
        const float* __restrict__ W_init_c, const float* __restrict__ b_init_c,
        float* __restrict__ h0, float* __restrict__ c0) {
    int b = blockIdx.x, tid = threadIdx.x;
    __shared__ float avg[ENC_];
    for (int e = tid; e < ENC_; e += 256) {
        float s = 0.f;
        const float* p = enc + (size_t)b * P_ * ENC_ + e;
        for (int i = 0; i < P_; i++) s += p[(size_t)i * ENC_];
        avg[e] = s * (1.0f / (float)P_);
    }
    __syncthreads();
    int d = tid;  // 256 threads == DEC_
    float hs = b_init_h[d], cs = b_init_c[d];
    const float* wh = W_init_h + (size_t)d * ENC_;
    const float* wc = W_init_c + (size_t)d * ENC_;
    for (int e = 0; e < ENC_; e++) { float a = avg[e]; hs += a * wh[e]; cs += a * wc[e]; }
    h0[b * DEC_ + d] = hs;
    c0[b * DEC_ + d] = cs;
}

// ---------- att1h via fp16 MFMA: C[a][p] = sum_e Wea[a][e] * enc[b][p][e] ----------
// att1h[b][a2][208 p] = h2{C[2a2][p], C[2a2+1][p]}. grid (2 p-tiles, 2 a-tiles, 64 b) x 256.
__global__ __launch_bounds__(256) void k_att1(
        const float* __restrict__ enc, const float* __restrict__ Wea,
        unsigned int* __restrict__ att1h) {
    int n0 = blockIdx.x * 128;   // p tile
    int m0 = blockIdx.y * 128;   // a tile
    int b  = blockIdx.z;
    __shared__ __align__(16) unsigned short At[128][40];  // [a][k] fp16
    __shared__ __align__(16) unsigned short Bt[128][40];  // [p][k] fp16
    int tid = threadIdx.x;
    int lane = tid & 63, w = tid >> 6;
    int wm = (w & 1) * 64, wn = (w >> 1) * 64;
    f32x4 acc[4][4];
#pragma unroll
    for (int i = 0; i < 4; i++)
#pragma unroll
        for (int j = 0; j < 4; j++) acc[i][j] = (f32x4){0.f, 0.f, 0.f, 0.f};

    for (int k0 = 0; k0 < ENC_; k0 += 32) {
#pragma unroll
        for (int l = 0; l < 2; l++) {
            int idx = l * 256 + tid;          // 0..511
            int r = idx >> 2, kc = (idx & 3) * 8;
            // A: Wea row a = m0 + r (always < 256)
            const float* ap = Wea + (size_t)(m0 + r) * ENC_ + k0 + kc;
            float4 f0 = *reinterpret_cast<const float4*>(ap);
            float4 f1 = *reinterpret_cast<const float4*>(ap + 4);
            uint4 av;
            av.x = pkh2(f0.x, f0.y); av.y = pkh2(f0.z, f0.w);
            av.z = pkh2(f1.x, f1.y); av.w = pkh2(f1.z, f1.w);
            *reinterpret_cast<uint4*>(&At[r][kc]) = av;
            // B: enc row p = n0 + r
            uint4 bv = make_uint4(0u, 0u, 0u, 0u);
            int p = n0 + r;
            if (p < P_) {
                const float* bp = enc + ((size_t)b * P_ + p) * ENC_ + k0 + kc;
                float4 g0 = *reinterpret_cast<const float4*>(bp);
                float4 g1 = *reinterpret_cast<const float4*>(bp + 4);
                bv.x = pkh2(g0.x, g0.y); bv.y = pkh2(g0.z, g0.w);
                bv.z = pkh2(g1.x, g1.y); bv.w = pkh2(g1.z, g1.w);
            }
            *reinterpret_cast<uint4*>(&Bt[r][kc]) = bv;
        }
        __syncthreads();
        int qk = (lane >> 4) * 8, fr = lane & 15;
        half8 a[4], bb[4];
#pragma unroll
        for (int i = 0; i < 4; i++) {
            a[i]  = *reinterpret_cast<const half8*>(&At[wm + i * 16 + fr][qk]);
            bb[i] = *reinterpret_cast<const half8*>(&Bt[wn + i * 16 + fr][qk]);
        }
#pragma unroll
        for (int i = 0; i < 4; i++)
#pragma unroll
            for (int j = 0; j < 4; j++)
                acc[i][j] = __builtin_amdgcn_mfma_f32_16x16x32_f16(a[i], bb[j], acc[i][j], 0, 0, 0);
        __syncthreads();
    }
    unsigned int* eb = att1h + (size_t)b * A1N_;
    int col = lane & 15, qr = (lane >> 4) * 4;
#pragma unroll
    for (int j = 0; j < 4; j++) {
        int p = n0 + wn + j * 16 + col;
        if (p < 208) {
#pragma unroll
            for (int i = 0; i < 4; i++) {
                int a0r = m0 + wm + i * 16 + qr;   // even
                eb[(size_t)(a0r >> 1) * 208 + p]       = pkh2(acc[i][j][0], acc[i][j][1]);
                eb[(size_t)((a0r >> 1) + 1) * 208 + p] = pkh2(acc[i][j][2], acc[i][j][3]);
            }
        }
    }
}

// ---------- embW[(t*64+b)][j] = b_ih[j]+b_hh[j] + sum_e emb[cap(b,t)][e]*W_ih[j][512+e] ----------
__global__ __launch_bounds__(256) void k_embW(
        const int* __restrict__ caption, const float* __restrict__ embedding,
        const float* __restrict__ WiheT, const float* __restrict__ b_ih,
        const float* __restrict__ b_hh, float* __restrict__ embW) {
    int r0 = blockIdx.x * 16, tid = threadIdx.x;
    __shared__ float embL[16][256];
    __shared__ int capL[16];
    if (tid < 16) {
        int r = r0 + tid, t = r >> 6, b = r & 63;
        capL[tid] = caption[b * T_ + t];
    }
    __syncthreads();
#pragma unroll
    for (int lr = 0; lr < 16; lr++)
        embL[lr][tid] = embedding[(size_t)capL[lr] * EMB_ + tid];
    __syncthreads();
    float base0 = b_ih[tid] + b_hh[tid];
    float base1 = b_ih[tid + 256] + b_hh[tid + 256];
    float base2 = b_ih[tid + 512] + b_hh[tid + 512];
    float base3 = b_ih[tid + 768] + b_hh[tid + 768];
    float acc[16][4];
#pragma unroll
    for (int lr = 0; lr < 16; lr++) {
        acc[lr][0] = base0; acc[lr][1] = base1; acc[lr][2] = base2; acc[lr][3] = base3;
    }
    for (int e = 0; e < EMB_; e++) {
        const float* wr = WiheT + (size_t)e * G4_ + tid;
        float w0 = wr[0], w1 = wr[256], w2 = wr[512], w3 = wr[768];
#pragma unroll
        for (int lr = 0; lr < 16; lr++) {
            float ev = embL[lr][e];
            acc[lr][0] += w0 * ev; acc[lr][1] += w1 * ev;
            acc[lr][2] += w2 * ev; acc[lr][3] += w3 * ev;
        }
    }
#pragma unroll
    for (int lr = 0; lr < 16; lr++) {
        float* o = embW + (size_t)(r0 + lr) * G4_ + tid;
        o[0] = acc[lr][0]; o[256] = acc[lr][1]; o[512] = acc[lr][2]; o[768] = acc[lr][3];
    }
}

// ---------- the sequential recurrence: one block (1024 thr = 16 waves) per b ----------
// Grid is 64 blocks on 256 CUs -> exactly 1 block/CU; 2-blocks/CU occupancy is unreachable.
// amdgpu_waves_per_eu(4,4) pins the allocator to 4 waves/EU so the VGPR budget is 128
// (launch_bounds' min alone let it target 8 waves/EU -> 64 VGPRs -> a1r/gPre spilled, R8).
__global__ __launch_bounds__(1024)
__attribute__((amdgpu_waves_per_eu(4, 4)))
void k_recur(
        const unsigned int* __restrict__ att1h, const float4* __restrict__ WdaP4,
        const float* __restrict__ W_full, const float4* __restrict__ Wg4,
        const float* __restrict__ embW, const uint2* __restrict__ encPh,
        const float* __restrict__ h0, const float* __restrict__ c0,
        unsigned short* __restrict__ Hbf, float* __restrict__ out_alpha) {
    int b = blockIdx.x, tid = threadIdx.x;
    int q = tid >> 8;        // 0..3 k-split group
    int r = tid & 255;
    int e5 = tid & 511, ph = tid >> 9;

    __shared__ __align__(16) float h_l[DEC_];
    __shared__ __align__(16) float att2_l[ATT_];
    __shared__ __align__(16) float wf_l[ATT_];
    __shared__ __align__(16) _Float16 xh[XW_];     // [ctx fp16(512); h fp16(256)]
    __shared__ __align__(8)  _Float16 alpha_h[208];
    __shared__ float p1[4][256];
    __shared__ float p2[4][256];
    __shared__ float p3[2][512];
    __shared__ __align__(16) float4 p4s[4][256];

    // att1 rows for this thread's (q, r), loop-invariant over t -> registers (32 u32)
    unsigned int a1r[32];
    {
        int rc = (r < 208) ? r : 207;
        const unsigned int* a1g = att1h + (size_t)b * A1N_ + (size_t)(q * 32) * 208 + rc;
#pragma unroll
        for (int i = 0; i < 32; i++) a1r[i] = a1g[(size_t)i * 208];
    }
    if (tid < 256) {
        float hv = h0[b * DEC_ + tid];
        h_l[tid] = hv;
        xh[512 + tid] = (_Float16)hv;
        wf_l[tid] = W_full[tid];
    }
    float c = (tid < 256) ? c0[b * DEC_ + tid] : 0.f;
    __syncthreads();

    const uint2* encb = encPh + (size_t)b * (49 * ENC_);

    for (int t = 0; t < T_; ++t) {
        // ---- P1: att2 partial over d in [q*64,(q+1)*64), thread r = a (fp32)
        float a2 = 0.f;
#pragma unroll 4
        for (int i = 0; i < 16; i++) {
            int d4 = q * 16 + i;
            float4 w = WdaP4[(size_t)d4 * 256 + r];
            float4 h4 = *reinterpret_cast<const float4*>(&h_l[4 * d4]);
            a2 += w.x * h4.x + w.y * h4.y + w.z * h4.z + w.w * h4.w;
        }
        p1[q][r] = a2;
        bar();
        if (tid < 256) att2_l[tid] = p1[0][tid] + p1[1][tid] + p1[2][tid] + p1[3][tid];
        bar();

        // ---- P2: score partial over a-pairs in [q*32,(q+1)*32), att1 from registers
        float sp = 0.f;
#pragma unroll
        for (int i = 0; i < 32; i++) {
            int a2i = q * 32 + i;
            f16x2 av = __builtin_bit_cast(f16x2, a1r[i]);
            float2 t2 = *reinterpret_cast<const float2*>(&att2_l[2 * a2i]);
            float2 w4 = *reinterpret_cast<const float2*>(&wf_l[2 * a2i]);
            sp += fmaxf((float)av.x + t2.x, 0.f) * w4.x +
                  fmaxf((float)av.y + t2.y, 0.f) * w4.y;
        }
        p2[q][r] = sp;
        // prefetch P4's first weight chunk (addresses static; stays in flight across bars)
        float4 gPre[6];
#pragma unroll
        for (int i = 0; i < 6; i++) gPre[i] = Wg4[(size_t)(q * 96 + i) * 256 + r];
        bar();

        // ---- fused softmax: every wave redundantly computes the denominator (no extra bar)
        float sden = 0.f;
        {
            int l = tid & 63;
#pragma unroll
            for (int cq = 0; cq < 4; cq++) {
                int cc = l + cq * 64;
                float s = p2[0][cc] + p2[1][cc] + p2[2][cc] + p2[3][cc];
                sden += (cc < P_) ? __expf(s) : 0.f;
            }
#pragma unroll
            for (int off = 32; off; off >>= 1) sden += __shfl_xor(sden, off);
        }
        if (tid < 256) {
            float s = p2[0][tid] + p2[1][tid] + p2[2][tid] + p2[3][tid];
            float ex = (tid < P_) ? __expf(s) : 0.f;
            float alpha = ex / sden;         // == 0 for tid >= P_
            if (tid < 208) alpha_h[tid] = (_Float16)alpha;
            if (tid < P_) out_alpha[(size_t)b * (T_ * P_) + t * P_ + tid] = alpha;
        }
        bar();

        // ---- P3: ctx partial, thread e = e5, p4 split 2-way (fp16 enc, fdot2)
        float cx = 0.f;
        {
            int p4b = ph ? 25 : 0, p4e = ph ? 49 : 25;
#pragma unroll 5
            for (int p4 = p4b; p4 < p4e; p4++) {
                uint2 ev = encb[(size_t)p4 * ENC_ + e5];
                f16x2 a01 = *reinterpret_cast<const f16x2*>(&alpha_h[4 * p4]);
                f16x2 a23 = *reinterpret_cast<const f16x2*>(&alpha_h[4 * p4 + 2]);
                cx = fdot2u(ev.x, a01, cx);
                cx = fdot2u(ev.y, a23, cx);
            }
        }
        p3[ph][e5] = cx;
        // embW row prefetch (used in P5; 4 VGPRs held across P4)
        float ew0 = 0.f, ew1 = 0.f, ew2 = 0.f, ew3 = 0.f;
        if (tid < 256) {
            const float* ew = embW + ((size_t)t * B_ + b) * G4_;
            ew0 = ew[tid]; ew1 = ew[tid + 256]; ew2 = ew[tid + 512]; ew3 = ew[tid + 768];
        }
        bar();
        if (tid < 512) xh[tid] = (_Float16)(p3[0][tid] + p3[1][tid]);
        bar();

        // ---- P4: gates, k2 in [q*96,(q+1)*96), fp16 weights, thread r = d (fdot2)
        float4 acc = {0.f, 0.f, 0.f, 0.f};
#pragma unroll
        for (int i = 0; i < 6; i++) {
            int k2 = q * 96 + i;
            f16x2 xv = *reinterpret_cast<const f16x2*>(&xh[2 * k2]);
            acc.x = fdot2f(gPre[i].x, xv, acc.x);
            acc.y = fdot2f(gPre[i].y, xv, acc.y);
            acc.z = fdot2f(gPre[i].z, xv, acc.z);
            acc.w = fdot2f(gPre[i].w, xv, acc.w);
        }
#pragma unroll 6
        for (int i = 6; i < 96; i++) {
            int k2 = q * 96 + i;
            float4 w = Wg4[(size_t)k2 * 256 + r];
            f16x2 xv = *reinterpret_cast<const f16x2*>(&xh[2 * k2]);
            acc.x = fdot2f(w.x, xv, acc.x);
            acc.y = fdot2f(w.y, xv, acc.y);
            acc.z = fdot2f(w.z, xv, acc.z);
            acc.w = fdot2f(w.w, xv, acc.w);
        }
        p4s[q][r] = acc;
        bar();

        // ---- P5: reduce partials + LSTM pointwise (torch gate order i,f,g,o)
        if (tid < 256) {
            float4 g0 = p4s[0][tid], g1 = p4s[1][tid], g2 = p4s[2][tid], g3 = p4s[3][tid];
            float gi = g0.x + g1.x + g2.x + g3.x + ew0;
            float gf = g0.y + g1.y + g2.y + g3.y + ew1;
            float gg = g0.z + g1.z + g2.z + g3.z + ew2;
            float go = g0.w + g1.w + g2.w + g3.w + ew3;
            float i_g = 1.f / (1.f + __expf(-gi));
            float f_g = 1.f / (1.f + __expf(-gf));
            float g_g = tanhf(gg);
            float o_g = 1.f / (1.f + __expf(-go));
            c = f_g * c + i_g * g_g;
            float hn = o_g * tanhf(c);
            h_l[tid] = hn;
            xh[512 + tid] = (_Float16)hn;
            Hbf[((size_t)t * B_ + b) * DEC_ + tid] = f2bf(hn);
        }
        bar();
    }
}

// ---------- logits: C[m][n] = H[m,:] . Wout[n,:] + b_out[n], bf16 MFMA ----------
__global__ __launch_bounds__(256) void k_logits(
        const unsigned short* __restrict__ Hbf, const unsigned short* __restrict__ Woutbf,
        const float* __restrict__ b_out, float* __restrict__ out) {
    int n0 = blockIdx.x * 128, m0 = blockIdx.y * 128;
    __shared__ __align__(16) unsigned short At[128][40];
    __shared__ __align__(16) unsigned short Bt[128][40];
    int tid = threadIdx.x;
    int lane = tid & 63, w = tid >> 6;
    int wm = (w & 1) * 64, wn = (w >> 1) * 64;
    f32x4 acc[4][4];
#pragma unroll
    for (int i = 0; i < 4; i++)
#pragma unroll
        for (int j = 0; j < 4; j++) acc[i][j] = (f32x4){0.f, 0.f, 0.f, 0.f};

    for (int k0 = 0; k0 < DEC_; k0 += 32) {
#pragma unroll
        for (int l = 0; l < 2; l++) {
            int idx = l * 256 + tid;         // 0..511
            int r = idx >> 2, kc = (idx & 3) * 8;
            uint4 av = *reinterpret_cast<const uint4*>(&Hbf[(size_t)(m0 + r) * DEC_ + k0 + kc]);
            *reinterpret_cast<uint4*>(&At[r][kc]) = av;
            uint4 bv = make_uint4(0u, 0u, 0u, 0u);
            if (n0 + r < V_)
                bv = *reinterpret_cast<const uint4*>(&Woutbf[(size_t)(n0 + r) * DEC_ + k0 + kc]);
            *reinterpret_cast<uint4*>(&Bt[r][kc]) = bv;
        }
        __syncthreads();
        int qk = (lane >> 4) * 8, fr = lane & 15;
        short8 a[4], bb[4];
#pragma unroll
        for (int i = 0; i < 4; i++) {
            a[i]  = *reinterpret_cast<const short8*>(&At[wm + i * 16 + fr][qk]);
            bb[i] = *reinterpret_cast<const short8*>(&Bt[wn + i * 16 + fr][qk]);
        }
#pragma unroll
        for (int i = 0; i < 4; i++)
#pragma unroll
            for (int j = 0; j < 4; j++)
                acc[i][j] = __builtin_amdgcn_mfma_f32_16x16x32_bf16(a[i], bb[j], acc[i][j], 0, 0, 0);
        __syncthreads();
    }
    int col = lane & 15, qr = (lane >> 4) * 4;
#pragma unroll
    for (int j = 0; j < 4; j++) {
        int n = n0 + wn + j * 16 + col;
        if (n < V_) {
            float bo = b_out[n];
#pragma unroll
            for (int i = 0; i < 4; i++)
#pragma unroll
                for (int rr = 0; rr < 4; rr++) {
                    int m = m0 + wm + i * 16 + qr + rr;
                    int t = m >> 6, bb2 = m & 63;
                    out[(size_t)bb2 * (T_ * V_) + (size_t)t * V_ + n] = acc[i][j][rr] + bo;
                }
        }
    }
}

// ---------- launch ----------
extern "C" void kernel_launch(void* const* d_in, const int* in_sizes, int n_in,
                              void* d_out, int out_size, void* d_ws, size_t ws_size,
                              hipStream_t stream) {
    const float* enc       = (const float*)d_in[0];
    const int*   caption   = (const int*)d_in[1];
    const float* W_enc_att = (const float*)d_in[2];
    const float* W_dec_att = (const float*)d_in[3];
    const float* W_full    = (const float*)d_in[4];
    const float* embedding = (const float*)d_in[5];
    const float* W_init_h  = (const float*)d_in[6];
    const float* b_init_h  = (const float*)d_in[7];
    const float* W_init_c  = (const float*)d_in[8];
    const float* b_init_c  = (const float*)d_in[9];
    const float* W_ih      = (const float*)d_in[10];
    const float* b_ih      = (const float*)d_in[11];
    const float* W_hh      = (const float*)d_in[12];
    const float* b_hh      = (const float*)d_in[13];
    const float* W_out     = (const float*)d_in[14];
    const float* b_out     = (const float*)d_in[15];

    float* ws = (float*)d_ws;
    float* h0    = ws;                    //      16384
    float* c0    = ws + 16384;            //      16384
    float* WdaP  = ws + 32768;            //      65536  [64 d4][256 a] float4
    float* WiheT = ws + 98304;            //     262144  [256 e][1024 j]
    float* Wg4   = ws + 360448;           //     393216  [384 k2][256 d] 4x half2
    float* embW  = ws + 753664;           //    2883584  [t*64+b][1024]
    float* att1h = ws + 3637248;          //    1703936  [b][128 a2][208 p] f16x2 (u32)
    float* encPh = ws + 5341184;          //    3211264  [b][49 p4][512 e] uint2 fp16
    unsigned short* Hbf    = (unsigned short*)(ws + 8552448);   // 2816*256 bf16 = 360448 fl
    unsigned short* Woutbf = (unsigned short*)(ws + 8912896);   // 10000*256 bf16 = 1280000 fl
    // total: 8912896 + 1280000 = 10192896 floats ~= 40.8 MB

    float* out_pred  = (float*)d_out;
    float* out_alpha = out_pred + (size_t)B_ * T_ * V_;

    k_transpose<<<dim3(8, 32), 256, 0, stream>>>(W_ih, WiheT, G4_, XW_, ENC_);
    k_packWda<<<64, 256, 0, stream>>>(W_dec_att, (float4*)WdaP);
    k_packWg<<<384, 256, 0, stream>>>(W_ih, W_hh, (float4*)Wg4);
    k_packenc<<<dim3(64, 7), 256, 0, stream>>>(enc, (uint2*)encPh);
    k_cvt<<<10000, 256, 0, stream>>>(W_out, Woutbf, V_ * DEC_);
    k_init_state<<<B_, 256, 0, stream>>>(enc, W_init_h, b_init_h, W_init_c, b_init_c, h0, c0);
    k_att1<<<dim3(2, 2, 64), 256, 0, stream>>>(enc, W_enc_att, (unsigned int*)att1h);
    k_embW<<<176, 256, 0, stream>>>(caption, embedding, WiheT, b_ih, b_hh, embW);
    k_recur<<<B_, 1024, 0, stream>>>((const unsigned int*)att1h, (const float4*)WdaP, W_full,
                                     (const float4*)Wg4, embW, (const uint2*)encPh,
                                     h0, c0, Hbf, out_alpha);
    k_logits<<<dim3(79, 22), 256, 0, stream>>>(Hbf, Woutbf, b_out, out_pred);
}

// Round 10
// 1309.194 us; speedup vs baseline: 1.6809x; 1.6809x over previous
//
#include <hip/hip_runtime.h>

// ---------- constants ----------
#define B_   64
#define P_   196
#define ENC_ 512
#define ATT_ 256
#define DEC_ 256
#define EMB_ 256
#define V_   10000
#define T_   44
#define G4_  1024          // 4*DEC
#define XW_  768           // EMB+ENC (W_ih inner dim)
#define A1N_ 26624         // att1h per-b u32 count: 128 a2 * 208 p

using short8 = __attribute__((ext_vector_type(8))) short;
using half8  = __attribute__((ext_vector_type(8))) _Float16;
using f32x4  = __attribute__((ext_vector_type(4))) float;
typedef _Float16 f16x2 __attribute__((ext_vector_type(2)));

__device__ __forceinline__ unsigned short f2bf(float f) {
    unsigned int u = __float_as_uint(f);
    unsigned int r = (u + 0x7fffu + ((u >> 16) & 1u)) >> 16;
    return (unsigned short)r;
}

__device__ __forceinline__ unsigned int pkh2(float a, float b) {
    f16x2 t; t.x = (_Float16)a; t.y = (_Float16)b;
    return __builtin_bit_cast(unsigned int, t);
}

// fp16x2 dot with fp32 accumulate (single V_DOT2_F32_F16 where available)
__device__ __forceinline__ float fdot2f(float wbits, f16x2 xv, float acc) {
    f16x2 wv = __builtin_bit_cast(f16x2, wbits);
#if __has_builtin(__builtin_amdgcn_fdot2)
    return __builtin_amdgcn_fdot2(wv, xv, acc, false);
#else
    acc = fmaf((float)wv.x, (float)xv.x, acc);
    acc = fmaf((float)wv.y, (float)xv.y, acc);
    return acc;
#endif
}
__device__ __forceinline__ float fdot2u(unsigned int wbits, f16x2 xv, float acc) {
    f16x2 wv = __builtin_bit_cast(f16x2, wbits);
#if __has_builtin(__builtin_amdgcn_fdot2)
    return __builtin_amdgcn_fdot2(wv, xv, acc, false);
#else
    acc = fmaf((float)wv.x, (float)xv.x, acc);
    acc = fmaf((float)wv.y, (float)xv.y, acc);
    return acc;
#endif
}

// raw barrier: drains LDS ops only; global loads stay in flight (T4).
__device__ __forceinline__ void bar() {
    asm volatile("s_waitcnt lgkmcnt(0)" ::: "memory");
    __builtin_amdgcn_s_barrier();
    asm volatile("" ::: "memory");
}

// ---------- generic 32x32 transpose: dst[k*N + n] = src[n*stride + off + k] ----------
__global__ void k_transpose(const float* __restrict__ src, float* __restrict__ dst,
                            int N, int stride, int off) {
    __shared__ float t[32][33];
    int k0 = blockIdx.x * 32, n0 = blockIdx.y * 32;
    int tx = threadIdx.x & 31, ty = threadIdx.x >> 5;
    for (int r = ty; r < 32; r += 8)
        t[r][tx] = src[(size_t)(n0 + r) * stride + off + k0 + tx];
    __syncthreads();
    for (int r = ty; r < 32; r += 8)
        dst[(size_t)(k0 + r) * N + n0 + tx] = t[tx][r];
}

// ---------- pack W_dec_att [a][d] -> WdaP4[d4*256+a] = {W[a][4d4..4d4+3]} ----------
__global__ __launch_bounds__(256) void k_packWda(const float* __restrict__ Wda,
                                                 float4* __restrict__ WdaP4) {
    int d4 = blockIdx.x, a = threadIdx.x;
    float4 v;
    v.x = Wda[(size_t)a * DEC_ + 4 * d4 + 0];
    v.y = Wda[(size_t)a * DEC_ + 4 * d4 + 1];
    v.z = Wda[(size_t)a * DEC_ + 4 * d4 + 2];
    v.w = Wda[(size_t)a * DEC_ + 4 * d4 + 3];
    WdaP4[(size_t)d4 * 256 + a] = v;
}

// ---------- pack gate weights fp16: Wg4[k2*256+d] = 4 gates x half2(k=2k2,2k2+1) ----------
// k<512 -> W_ih[:, k] (ctx part); k>=512 -> W_hh[:, k-512] (h part). grid 384 x 256.
__global__ __launch_bounds__(256) void k_packWg(const float* __restrict__ Wih,
        const float* __restrict__ Whh, float4* __restrict__ Wg4) {
    int k2 = blockIdx.x, d = threadIdx.x;
    int k = 2 * k2;
    unsigned int o[4];
#pragma unroll
    for (int g = 0; g < 4; ++g) {
        int row = g * 256 + d;
        float a0, a1;
        if (k < ENC_) {
            a0 = Wih[(size_t)row * XW_ + k];
            a1 = Wih[(size_t)row * XW_ + k + 1];
        } else {
            a0 = Whh[(size_t)row * DEC_ + k - ENC_];
            a1 = Whh[(size_t)row * DEC_ + k - ENC_ + 1];
        }
        o[g] = pkh2(a0, a1);
    }
    float4 v;
    v.x = __builtin_bit_cast(float, o[0]);
    v.y = __builtin_bit_cast(float, o[1]);
    v.z = __builtin_bit_cast(float, o[2]);
    v.w = __builtin_bit_cast(float, o[3]);
    Wg4[(size_t)k2 * 256 + d] = v;
}

// ---------- pack enc fp16: encPh[(b*49+p4)*512+e] = uint2{h2(p=4p4,4p4+1), h2(4p4+2,4p4+3)} ----------
// grid: (64 b, 7), each y handles 7 p4 values
__global__ __launch_bounds__(256) void k_packenc(const float* __restrict__ enc,
                                                 uint2* __restrict__ encPh) {
    int b = blockIdx.x, p4b = blockIdx.y * 7;
    for (int p4 = p4b; p4 < p4b + 7; ++p4) {
        for (int e = threadIdx.x; e < ENC_; e += 256) {
            float a0 = enc[((size_t)b * P_ + 4 * p4 + 0) * ENC_ + e];
            float a1 = enc[((size_t)b * P_ + 4 * p4 + 1) * ENC_ + e];
            float a2 = enc[((size_t)b * P_ + 4 * p4 + 2) * ENC_ + e];
            float a3 = enc[((size_t)b * P_ + 4 * p4 + 3) * ENC_ + e];
            uint2 v; v.x = pkh2(a0, a1); v.y = pkh2(a2, a3);
            encPh[((size_t)b * 49 + p4) * ENC_ + e] = v;
        }
    }
}

// ---------- fp32 -> bf16 convert ----------
__global__ void k_cvt(const float* __restrict__ src, unsigned short* __restrict__ dst, int n) {
    int i = blockIdx.x * 256 + threadIdx.x;
    if (i < n) dst[i] = f2bf(src[i]);
}

// ---------- h0/c0 from mean-pooled encoder ----------
__global__ __launch_bounds__(256) void k_init_state(
        const float* __restrict__ enc,
        const float* __restrict__ W_init_h, const float* __restrict__ b_init_h,
        const float* __restrict__ W_init_c, const float* __restrict__ b_init_c,
        float* __restrict__ h0, float* __restrict__ c0) {
    int b = blockIdx.x, tid = threadIdx.x;
    __shared__ float avg[ENC_];
    for (int e = tid; e < ENC_; e += 256) {
        float s = 0.f;
        const float* p = enc + (size_t)b * P_ * ENC_ + e;
        for (int i = 0; i < P_; i++) s += p[(size_t)i * ENC_];
        avg[e] = s * (1.0f / (float)P_);
    }
    __syncthreads();
    int d = tid;  // 256 threads == DEC_
    float hs = b_init_h[d], cs = b_init_c[d];
    const float* wh = W_init_h + (size_t)d * ENC_;
    const float* wc = W_init_c + (size_t)d * ENC_;
    for (int e = 0; e < ENC_; e++) { float a = avg[e]; hs += a * wh[e]; cs += a * wc[e]; }
    h0[b * DEC_ + d] = hs;
    c0[b * DEC_ + d] = cs;
}

// ---------- att1h via fp16 MFMA: C[a][p] = sum_e Wea[a][e] * enc[b][p][e] ----------
// att1h[b][a2][208 p] = h2{C[2a2][p], C[2a2+1][p]}. grid (2 p-tiles, 2 a-tiles, 64 b) x 256.
__global__ __launch_bounds__(256) void k_att1(
        const float* __restrict__ enc, const float* __restrict__ Wea,
        unsigned int* __restrict__ att1h) {
    int n0 = blockIdx.x * 128;   // p tile
    int m0 = blockIdx.y * 128;   // a tile
    int b  = blockIdx.z;
    __shared__ __align__(16) unsigned short At[128][40];  // [a][k] fp16
    __shared__ __align__(16) unsigned short Bt[128][40];  // [p][k] fp16
    int tid = threadIdx.x;
    int lane = tid & 63, w = tid >> 6;
    int wm = (w & 1) * 64, wn = (w >> 1) * 64;
    f32x4 acc[4][4];
#pragma unroll
    for (int i = 0; i < 4; i++)
#pragma unroll
        for (int j = 0; j < 4; j++) acc[i][j] = (f32x4){0.f, 0.f, 0.f, 0.f};

    for (int k0 = 0; k0 < ENC_; k0 += 32) {
#pragma unroll
        for (int l = 0; l < 2; l++) {
            int idx = l * 256 + tid;          // 0..511
            int r = idx >> 2, kc = (idx & 3) * 8;
            // A: Wea row a = m0 + r (always < 256)
            const float* ap = Wea + (size_t)(m0 + r) * ENC_ + k0 + kc;
            float4 f0 = *reinterpret_cast<const float4*>(ap);
            float4 f1 = *reinterpret_cast<const float4*>(ap + 4);
            uint4 av;
            av.x = pkh2(f0.x, f0.y); av.y = pkh2(f0.z, f0.w);
            av.z = pkh2(f1.x, f1.y); av.w = pkh2(f1.z, f1.w);
            *reinterpret_cast<uint4*>(&At[r][kc]) = av;
            // B: enc row p = n0 + r
            uint4 bv = make_uint4(0u, 0u, 0u, 0u);
            int p = n0 + r;
            if (p < P_) {
                const float* bp = enc + ((size_t)b * P_ + p) * ENC_ + k0 + kc;
                float4 g0 = *reinterpret_cast<const float4*>(bp);
                float4 g1 = *reinterpret_cast<const float4*>(bp + 4);
                bv.x = pkh2(g0.x, g0.y); bv.y = pkh2(g0.z, g0.w);
                bv.z = pkh2(g1.x, g1.y); bv.w = pkh2(g1.z, g1.w);
            }
            *reinterpret_cast<uint4*>(&Bt[r][kc]) = bv;
        }
        __syncthreads();
        int qk = (lane >> 4) * 8, fr = lane & 15;
        half8 a[4], bb[4];
#pragma unroll
        for (int i = 0; i < 4; i++) {
            a[i]  = *reinterpret_cast<const half8*>(&At[wm + i * 16 + fr][qk]);
            bb[i] = *reinterpret_cast<const half8*>(&Bt[wn + i * 16 + fr][qk]);
        }
#pragma unroll
        for (int i = 0; i < 4; i++)
#pragma unroll
            for (int j = 0; j < 4; j++)
                acc[i][j] = __builtin_amdgcn_mfma_f32_16x16x32_f16(a[i], bb[j], acc[i][j], 0, 0, 0);
        __syncthreads();
    }
    unsigned int* eb = att1h + (size_t)b * A1N_;
    int col = lane & 15, qr = (lane >> 4) * 4;
#pragma unroll
    for (int j = 0; j < 4; j++) {
        int p = n0 + wn + j * 16 + col;
        if (p < 208) {
#pragma unroll
            for (int i = 0; i < 4; i++) {
                int a0r = m0 + wm + i * 16 + qr;   // even
                eb[(size_t)(a0r >> 1) * 208 + p]       = pkh2(acc[i][j][0], acc[i][j][1]);
                eb[(size_t)((a0r >> 1) + 1) * 208 + p] = pkh2(acc[i][j][2], acc[i][j][3]);
            }
        }
    }
}

// ---------- embW[(t*64+b)][j] = b_ih[j]+b_hh[j] + sum_e emb[cap(b,t)][e]*W_ih[j][512+e] ----------
__global__ __launch_bounds__(256) void k_embW(
        const int* __restrict__ caption, const float* __restrict__ embedding,
        const float* __restrict__ WiheT, const float* __restrict__ b_ih,
        const float* __restrict__ b_hh, float* __restrict__ embW) {
    int r0 = blockIdx.x * 16, tid = threadIdx.x;
    __shared__ float embL[16][256];
    __shared__ int capL[16];
    if (tid < 16) {
        int r = r0 + tid, t = r >> 6, b = r & 63;
        capL[tid] = caption[b * T_ + t];
    }
    __syncthreads();
#pragma unroll
    for (int lr = 0; lr < 16; lr++)
        embL[lr][tid] = embedding[(size_t)capL[lr] * EMB_ + tid];
    __syncthreads();
    float base0 = b_ih[tid] + b_hh[tid];
    float base1 = b_ih[tid + 256] + b_hh[tid + 256];
    float base2 = b_ih[tid + 512] + b_hh[tid + 512];
    float base3 = b_ih[tid + 768] + b_hh[tid + 768];
    float acc[16][4];
#pragma unroll
    for (int lr = 0; lr < 16; lr++) {
        acc[lr][0] = base0; acc[lr][1] = base1; acc[lr][2] = base2; acc[lr][3] = base3;
    }
    for (int e = 0; e < EMB_; e++) {
        const float* wr = WiheT + (size_t)e * G4_ + tid;
        float w0 = wr[0], w1 = wr[256], w2 = wr[512], w3 = wr[768];
#pragma unroll
        for (int lr = 0; lr < 16; lr++) {
            float ev = embL[lr][e];
            acc[lr][0] += w0 * ev; acc[lr][1] += w1 * ev;
            acc[lr][2] += w2 * ev; acc[lr][3] += w3 * ev;
        }
    }
#pragma unroll
    for (int lr = 0; lr < 16; lr++) {
        float* o = embW + (size_t)(r0 + lr) * G4_ + tid;
        o[0] = acc[lr][0]; o[256] = acc[lr][1]; o[512] = acc[lr][2]; o[768] = acc[lr][3];
    }
}

// ---------- the sequential recurrence: one block (1024 thr = 16 waves, 4 waves/EU) per b ----------
// R5 structure (att1 fp16 LDS-resident, loaded once; Wg4/WdaP shared L2-resident) -- measured
// 956 us, VGPR 52, zero spill. Only change vs R5: fused single-pass softmax (one less barrier).
__global__ __launch_bounds__(1024, 4) void k_recur(
        const unsigned int* __restrict__ att1h, const float4* __restrict__ WdaP4,
        const float* __restrict__ W_full, const float4* __restrict__ Wg4,
        const float* __restrict__ embW, const uint2* __restrict__ encPh,
        const float* __restrict__ h0, const float* __restrict__ c0,
        unsigned short* __restrict__ Hbf, float* __restrict__ out_alpha) {
    int b = blockIdx.x, tid = threadIdx.x;
    int q = tid >> 8;        // 0..3 k-split group
    int r = tid & 255;
    int e5 = tid & 511, ph = tid >> 9;

    __shared__ __align__(16) float h_l[DEC_];
    __shared__ __align__(16) float att2_l[ATT_];
    __shared__ __align__(16) float wf_l[ATT_];
    __shared__ __align__(16) _Float16 xh[XW_];     // [ctx fp16(512); h fp16(256)]
    __shared__ __align__(8)  _Float16 alpha_h[208];
    __shared__ float p1[4][256];
    __shared__ float p2[4][256];
    __shared__ float p3[2][512];
    __shared__ __align__(16) float4 p4s[4][256];
    // att1 fp16, resident for the whole kernel. +48 pad: P2 reads index up to 127*208+255.
    __shared__ unsigned int att1_lds[A1N_ + 48];

    // ---- stage att1 into LDS (once) + init state
    {
        const unsigned int* a1g = att1h + (size_t)b * A1N_;
        for (int i = tid; i < A1N_; i += 1024) att1_lds[i] = a1g[i];
    }
    if (tid < 256) {
        float hv = h0[b * DEC_ + tid];
        h_l[tid] = hv;
        xh[512 + tid] = (_Float16)hv;
        wf_l[tid] = W_full[tid];
    }
    float c = (tid < 256) ? c0[b * DEC_ + tid] : 0.f;
    __syncthreads();

    const uint2* encb = encPh + (size_t)b * (49 * ENC_);

    for (int t = 0; t < T_; ++t) {
        // ---- P1: att2 partial over d in [q*64,(q+1)*64), thread r = a (fp32)
        float a2 = 0.f;
#pragma unroll 4
        for (int i = 0; i < 16; i++) {
            int d4 = q * 16 + i;
            float4 w = WdaP4[(size_t)d4 * 256 + r];
            float4 h4 = *reinterpret_cast<const float4*>(&h_l[4 * d4]);
            a2 += w.x * h4.x + w.y * h4.y + w.z * h4.z + w.w * h4.w;
        }
        p1[q][r] = a2;
        bar();
        if (tid < 256) att2_l[tid] = p1[0][tid] + p1[1][tid] + p1[2][tid] + p1[3][tid];
        bar();

        // ---- P2: score partial over a-pairs in [q*32,(q+1)*32), thread r = p (LDS att1 fp16)
        float sp = 0.f;
#pragma unroll 4
        for (int i = 0; i < 32; i++) {
            int a2i = q * 32 + i;
            f16x2 av = __builtin_bit_cast(f16x2, att1_lds[a2i * 208 + r]);
            float2 t2 = *reinterpret_cast<const float2*>(&att2_l[2 * a2i]);
            float2 w4 = *reinterpret_cast<const float2*>(&wf_l[2 * a2i]);
            sp += fmaxf((float)av.x + t2.x, 0.f) * w4.x +
                  fmaxf((float)av.y + t2.y, 0.f) * w4.y;
        }
        p2[q][r] = sp;
        bar();

        // ---- fused softmax: every wave redundantly computes the denominator (no extra bar;
        //      no max-subtraction -- fp32 exp safe for these score magnitudes)
        float sden = 0.f;
        {
            int l = tid & 63;
#pragma unroll
            for (int cq = 0; cq < 4; cq++) {
                int cc = l + cq * 64;
                float s = p2[0][cc] + p2[1][cc] + p2[2][cc] + p2[3][cc];
                sden += (cc < P_) ? __expf(s) : 0.f;
            }
#pragma unroll
            for (int off = 32; off; off >>= 1) sden += __shfl_xor(sden, off);
        }
        if (tid < 256) {
            float s = p2[0][tid] + p2[1][tid] + p2[2][tid] + p2[3][tid];
            float ex = (tid < P_) ? __expf(s) : 0.f;
            float alpha = ex / sden;         // == 0 for tid >= P_
            if (tid < 208) alpha_h[tid] = (_Float16)alpha;
            if (tid < P_) out_alpha[(size_t)b * (T_ * P_) + t * P_ + tid] = alpha;
        }
        bar();

        // ---- P3: ctx partial, thread e = e5, p4 split 2-way (fp16 enc, fdot2)
        float cx = 0.f;
        {
            int p4b = ph ? 25 : 0, p4e = ph ? 49 : 25;
#pragma unroll 5
            for (int p4 = p4b; p4 < p4e; p4++) {
                uint2 ev = encb[(size_t)p4 * ENC_ + e5];
                f16x2 a01 = *reinterpret_cast<const f16x2*>(&alpha_h[4 * p4]);
                f16x2 a23 = *reinterpret_cast<const f16x2*>(&alpha_h[4 * p4 + 2]);
                cx = fdot2u(ev.x, a01, cx);
                cx = fdot2u(ev.y, a23, cx);
            }
        }
        p3[ph][e5] = cx;
        // embW row prefetch (used in P5; 4 VGPRs held across P4)
        float ew0 = 0.f, ew1 = 0.f, ew2 = 0.f, ew3 = 0.f;
        if (tid < 256) {
            const float* ew = embW + ((size_t)t * B_ + b) * G4_;
            ew0 = ew[tid]; ew1 = ew[tid + 256]; ew2 = ew[tid + 512]; ew3 = ew[tid + 768];
        }
        bar();
        if (tid < 512) xh[tid] = (_Float16)(p3[0][tid] + p3[1][tid]);
        bar();

        // ---- P4: gates, k2 in [q*96,(q+1)*96), fp16 weights, thread r = d (fdot2)
        float4 acc = {0.f, 0.f, 0.f, 0.f};
#pragma unroll 8
        for (int i = 0; i < 96; i++) {
            int k2 = q * 96 + i;
            float4 w = Wg4[(size_t)k2 * 256 + r];
            f16x2 xv = *reinterpret_cast<const f16x2*>(&xh[2 * k2]);
            acc.x = fdot2f(w.x, xv, acc.x);
            acc.y = fdot2f(w.y, xv, acc.y);
            acc.z = fdot2f(w.z, xv, acc.z);
            acc.w = fdot2f(w.w, xv, acc.w);
        }
        p4s[q][r] = acc;
        bar();

        // ---- P5: reduce partials + LSTM pointwise (torch gate order i,f,g,o)
        if (tid < 256) {
            float4 g0 = p4s[0][tid], g1 = p4s[1][tid], g2 = p4s[2][tid], g3 = p4s[3][tid];
            float gi = g0.x + g1.x + g2.x + g3.x + ew0;
            float gf = g0.y + g1.y + g2.y + g3.y + ew1;
            float gg = g0.z + g1.z + g2.z + g3.z + ew2;
            float go = g0.w + g1.w + g2.w + g3.w + ew3;
            float i_g = 1.f / (1.f + __expf(-gi));
            float f_g = 1.f / (1.f + __expf(-gf));
            float g_g = tanhf(gg);
            float o_g = 1.f / (1.f + __expf(-go));
            c = f_g * c + i_g * g_g;
            float hn = o_g * tanhf(c);
            h_l[tid] = hn;
            xh[512 + tid] = (_Float16)hn;
            Hbf[((size_t)t * B_ + b) * DEC_ + tid] = f2bf(hn);
        }
        bar();
    }
}

// ---------- logits: C[m][n] = H[m,:] . Wout[n,:] + b_out[n], bf16 MFMA ----------
__global__ __launch_bounds__(256) void k_logits(
        const unsigned short* __restrict__ Hbf, const unsigned short* __restrict__ Woutbf,
        const float* __restrict__ b_out, float* __restrict__ out) {
    int n0 = blockIdx.x * 128, m0 = blockIdx.y * 128;
    __shared__ __align__(16) unsigned short At[128][40];
    __shared__ __align__(16) unsigned short Bt[128][40];
    int tid = threadIdx.x;
    int lane = tid & 63, w = tid >> 6;
    int wm = (w & 1) * 64, wn = (w >> 1) * 64;
    f32x4 acc[4][4];
#pragma unroll
    for (int i = 0; i < 4; i++)
#pragma unroll
        for (int j = 0; j < 4; j++) acc[i][j] = (f32x4){0.f, 0.f, 0.f, 0.f};

    for (int k0 = 0; k0 < DEC_; k0 += 32) {
#pragma unroll
        for (int l = 0; l < 2; l++) {
            int idx = l * 256 + tid;         // 0..511
            int r = idx >> 2, kc = (idx & 3) * 8;
            uint4 av = *reinterpret_cast<const uint4*>(&Hbf[(size_t)(m0 + r) * DEC_ + k0 + kc]);
            *reinterpret_cast<uint4*>(&At[r][kc]) = av;
            uint4 bv = make_uint4(0u, 0u, 0u, 0u);
            if (n0 + r < V_)
                bv = *reinterpret_cast<const uint4*>(&Woutbf[(size_t)(n0 + r) * DEC_ + k0 + kc]);
            *reinterpret_cast<uint4*>(&Bt[r][kc]) = bv;
        }
        __syncthreads();
        int qk = (lane >> 4) * 8, fr = lane & 15;
        short8 a[4], bb[4];
#pragma unroll
        for (int i = 0; i < 4; i++) {
            a[i]  = *reinterpret_cast<const short8*>(&At[wm + i * 16 + fr][qk]);
            bb[i] = *reinterpret_cast<const short8*>(&Bt[wn + i * 16 + fr][qk]);
        }
#pragma unroll
        for (int i = 0; i < 4; i++)
#pragma unroll
            for (int j = 0; j < 4; j++)
                acc[i][j] = __builtin_amdgcn_mfma_f32_16x16x32_bf16(a[i], bb[j], acc[i][j], 0, 0, 0);
        __syncthreads();
    }
    int col = lane & 15, qr = (lane >> 4) * 4;
#pragma unroll
    for (int j = 0; j < 4; j++) {
        int n = n0 + wn + j * 16 + col;
        if (n < V_) {
            float bo = b_out[n];
#pragma unroll
            for (int i = 0; i < 4; i++)
#pragma unroll
                for (int rr = 0; rr < 4; rr++) {
                    int m = m0 + wm + i * 16 + qr + rr;
                    int t = m >> 6, bb2 = m & 63;
                    out[(size_t)bb2 * (T_ * V_) + (size_t)t * V_ + n] = acc[i][j][rr] + bo;
                }
        }
    }
}

// ---------- launch ----------
extern "C" void kernel_launch(void* const* d_in, const int* in_sizes, int n_in,
                              void* d_out, int out_size, void* d_ws, size_t ws_size,
                              hipStream_t stream) {
    const float* enc       = (const float*)d_in[0];
    const int*   caption   = (const int*)d_in[1];
    const float* W_enc_att = (const float*)d_in[2];
    const float* W_dec_att = (const float*)d_in[3];
    const float* W_full    = (const float*)d_in[4];
    const float* embedding = (const float*)d_in[5];
    const float* W_init_h  = (const float*)d_in[6];
    const float* b_init_h  = (const float*)d_in[7];
    const float* W_init_c  = (const float*)d_in[8];
    const float* b_init_c  = (const float*)d_in[9];
    const float* W_ih      = (const float*)d_in[10];
    const float* b_ih      = (const float*)d_in[11];
    const float* W_hh      = (const float*)d_in[12];
    const float* b_hh      = (const float*)d_in[13];
    const float* W_out     = (const float*)d_in[14];
    const float* b_out     = (const float*)d_in[15];

    float* ws = (float*)d_ws;
    float* h0    = ws;                    //      16384
    float* c0    = ws + 16384;            //      16384
    float* WdaP  = ws + 32768;            //      65536  [64 d4][256 a] float4
    float* WiheT = ws + 98304;            //     262144  [256 e][1024 j]
    float* Wg4   = ws + 360448;           //     393216  [384 k2][256 d] 4x half2
    float* embW  = ws + 753664;           //    2883584  [t*64+b][1024]
    float* att1h = ws + 3637248;          //    1703936  [b][128 a2][208 p] f16x2 (u32)
    float* encPh = ws + 5341184;          //    3211264  [b][49 p4][512 e] uint2 fp16
    unsigned short* Hbf    = (unsigned short*)(ws + 8552448);   // 2816*256 bf16 = 360448 fl
    unsigned short* Woutbf = (unsigned short*)(ws + 8912896);   // 10000*256 bf16 = 1280000 fl
    // total: 8912896 + 1280000 = 10192896 floats ~= 40.8 MB

    float* out_pred  = (float*)d_out;
    float* out_alpha = out_pred + (size_t)B_ * T_ * V_;

    k_transpose<<<dim3(8, 32), 256, 0, stream>>>(W_ih, WiheT, G4_, XW_, ENC_);
    k_packWda<<<64, 256, 0, stream>>>(W_dec_att, (float4*)WdaP);
    k_packWg<<<384, 256, 0, stream>>>(W_ih, W_hh, (float4*)Wg4);
    k_packenc<<<dim3(64, 7), 256, 0, stream>>>(enc, (uint2*)encPh);
    k_cvt<<<10000, 256, 0, stream>>>(W_out, Woutbf, V_ * DEC_);
    k_init_state<<<B_, 256, 0, stream>>>(enc, W_init_h, b_init_h, W_init_c, b_init_c, h0, c0);
    k_att1<<<dim3(2, 2, 64), 256, 0, stream>>>(enc, W_enc_att, (unsigned int*)att1h);
    k_embW<<<176, 256, 0, stream>>>(caption, embedding, WiheT, b_ih, b_hh, embW);
    k_recur<<<B_, 1024, 0, stream>>>((const unsigned int*)att1h, (const float4*)WdaP, W_full,
                                     (const float4*)Wg4, embW, (const uint2*)encPh,
                                     h0, c0, Hbf, out_alpha);
    k_logits<<<dim3(79, 22), 256, 0, stream>>>(Hbf, Woutbf, b_out, out_pred);
}

// Round 12
// 1175.528 us; speedup vs baseline: 1.8720x; 1.1137x over previous
//
#include <hip/hip_runtime.h>

// ---------- constants ----------
#define B_   64
#define P_   196
#define ENC_ 512
#define ATT_ 256
#define DEC_ 256
#define EMB_ 256
#define V_   10000
#define T_   44
#define G4_  1024          // 4*DEC
#define XW_  768           // EMB+ENC (W_ih inner dim)
#define A1N_ 26624         // att1h per-b u32 count: 128 a2 * 208 p

using short8 = __attribute__((ext_vector_type(8))) short;
using half8  = __attribute__((ext_vector_type(8))) _Float16;
using f32x4  = __attribute__((ext_vector_type(4))) float;
typedef _Float16 f16x2 __attribute__((ext_vector_type(2)));

__device__ __forceinline__ unsigned short f2bf(float f) {
    unsigned int u = __float_as_uint(f);
    unsigned int r = (u + 0x7fffu + ((u >> 16) & 1u)) >> 16;
    return (unsigned short)r;
}

__device__ __forceinline__ unsigned int pkh2(float a, float b) {
    f16x2 t; t.x = (_Float16)a; t.y = (_Float16)b;
    return __builtin_bit_cast(unsigned int, t);
}

// fp16x2 dot with fp32 accumulate (single V_DOT2_F32_F16 where available)
__device__ __forceinline__ float fdot2f(float wbits, f16x2 xv, float acc) {
    f16x2 wv = __builtin_bit_cast(f16x2, wbits);
#if __has_builtin(__builtin_amdgcn_fdot2)
    return __builtin_amdgcn_fdot2(wv, xv, acc, false);
#else
    acc = fmaf((float)wv.x, (float)xv.x, acc);
    acc = fmaf((float)wv.y, (float)xv.y, acc);
    return acc;
#endif
}
__device__ __forceinline__ float fdot2u(unsigned int wbits, f16x2 xv, float acc) {
    f16x2 wv = __builtin_bit_cast(f16x2, wbits);
#if __has_builtin(__builtin_amdgcn_fdot2)
    return __builtin_amdgcn_fdot2(wv, xv, acc, false);
#else
    acc = fmaf((float)wv.x, (float)xv.x, acc);
    acc = fmaf((float)wv.y, (float)xv.y, acc);
    return acc;
#endif
}

// raw barrier: drains LDS ops only; global loads stay in flight (T4).
__device__ __forceinline__ void bar() {
    asm volatile("s_waitcnt lgkmcnt(0)" ::: "memory");
    __builtin_amdgcn_s_barrier();
    asm volatile("" ::: "memory");
}

// ---------- generic 32x32 transpose: dst[k*N + n] = src[n*stride + off + k] ----------
__global__ void k_transpose(const float* __restrict__ src, float* __restrict__ dst,
                            int N, int stride, int off) {
    __shared__ float t[32][33];
    int k0 = blockIdx.x * 32, n0 = blockIdx.y * 32;
    int tx = threadIdx.x & 31, ty = threadIdx.x >> 5;
    for (int r = ty; r < 32; r += 8)
        t[r][tx] = src[(size_t)(n0 + r) * stride + off + k0 + tx];
    __syncthreads();
    for (int r = ty; r < 32; r += 8)
        dst[(size_t)(k0 + r) * N + n0 + tx] = t[tx][r];
}

// ---------- pack W_dec_att [a][d] -> WdaP4[d4*256+a] = {W[a][4d4..4d4+3]} ----------
__global__ __launch_bounds__(256) void k_packWda(const float* __restrict__ Wda,
                                                 float4* __restrict__ WdaP4) {
    int d4 = blockIdx.x, a = threadIdx.x;
    float4 v;
    v.x = Wda[(size_t)a * DEC_ + 4 * d4 + 0];
    v.y = Wda[(size_t)a * DEC_ + 4 * d4 + 1];
    v.z = Wda[(size_t)a * DEC_ + 4 * d4 + 2];
    v.w = Wda[(size_t)a * DEC_ + 4 * d4 + 3];
    WdaP4[(size_t)d4 * 256 + a] = v;
}

// ---------- pack gate weights fp16: Wg4[k2*256+d] = 4 gates x half2(k=2k2,2k2+1) ----------
// k<512 -> W_ih[:, k] (ctx part); k>=512 -> W_hh[:, k-512] (h part). grid 384 x 256.
__global__ __launch_bounds__(256) void k_packWg(const float* __restrict__ Wih,
        const float* __restrict__ Whh, float4* __restrict__ Wg4) {
    int k2 = blockIdx.x, d = threadIdx.x;
    int k = 2 * k2;
    unsigned int o[4];
#pragma unroll
    for (int g = 0; g < 4; ++g) {
        int row = g * 256 + d;
        float a0, a1;
        if (k < ENC_) {
            a0 = Wih[(size_t)row * XW_ + k];
            a1 = Wih[(size_t)row * XW_ + k + 1];
        } else {
            a0 = Whh[(size_t)row * DEC_ + k - ENC_];
            a1 = Whh[(size_t)row * DEC_ + k - ENC_ + 1];
        }
        o[g] = pkh2(a0, a1);
    }
    float4 v;
    v.x = __builtin_bit_cast(float, o[0]);
    v.y = __builtin_bit_cast(float, o[1]);
    v.z = __builtin_bit_cast(float, o[2]);
    v.w = __builtin_bit_cast(float, o[3]);
    Wg4[(size_t)k2 * 256 + d] = v;
}

// ---------- pack enc fp16: encPh[(b*49+p4)*512+e] = uint2{h2(p=4p4,4p4+1), h2(4p4+2,4p4+3)} ----------
// grid: (64 b, 7), each y handles 7 p4 values
__global__ __launch_bounds__(256) void k_packenc(const float* __restrict__ enc,
                                                 uint2* __restrict__ encPh) {
    int b = blockIdx.x, p4b = blockIdx.y * 7;
    for (int p4 = p4b; p4 < p4b + 7; ++p4) {
        for (int e = threadIdx.x; e < ENC_; e += 256) {
            float a0 = enc[((size_t)b * P_ + 4 * p4 + 0) * ENC_ + e];
            float a1 = enc[((size_t)b * P_ + 4 * p4 + 1) * ENC_ + e];
            float a2 = enc[((size_t)b * P_ + 4 * p4 + 2) * ENC_ + e];
            float a3 = enc[((size_t)b * P_ + 4 * p4 + 3) * ENC_ + e];
            uint2 v; v.x = pkh2(a0, a1); v.y = pkh2(a2, a3);
            encPh[((size_t)b * 49 + p4) * ENC_ + e] = v;
        }
    }
}

// ---------- fp32 -> bf16 convert ----------
__global__ void k_cvt(const float* __restrict__ src, unsigned short* __restrict__ dst, int n) {
    int i = blockIdx.x * 256 + threadIdx.x;
    if (i < n) dst[i] = f2bf(src[i]);
}

// ---------- zero the pair-sync flags (must precede k_recur in-stream, every launch) ----------
__global__ void k_zeroflags(unsigned int* __restrict__ f) {
    f[threadIdx.x] = 0u;
}

// ---------- h0/c0 from mean-pooled encoder ----------
__global__ __launch_bounds__(256) void k_init_state(
        const float* __restrict__ enc,
        const float* __restrict__ W_init_h, const float* __restrict__ b_init_h,
        const float* __restrict__ W_init_c, const float* __restrict__ b_init_c,
        float* __restrict__ h0, float* __restrict__ c0) {
    int b = blockIdx.x, tid = threadIdx.x;
    __shared__ float avg[ENC_];
    for (int e = tid; e < ENC_; e += 256) {
        float s = 0.f;
        const float* p = enc + (size_t)b * P_ * ENC_ + e;
        for (int i = 0; i < P_; i++) s += p[(size_t)i * ENC_];
        avg[e] = s * (1.0f / (float)P_);
    }
    __syncthreads();
    int d = tid;  // 256 threads == DEC_
    float hs = b_init_h[d], cs = b_init_c[d];
    const float* wh = W_init_h + (size_t)d * ENC_;
    const float* wc = W_init_c + (size_t)d * ENC_;
    for (int e = 0; e < ENC_; e++) { float a = avg[e]; hs += a * wh[e]; cs += a * wc[e]; }
    h0[b * DEC_ + d] = hs;
    c0[b * DEC_ + d] = cs;
}

// ---------- att1h via fp16 MFMA: C[a][p] = sum_e Wea[a][e] * enc[b][p][e] ----------
// att1h[b][a2][208 p] = h2{C[2a2][p], C[2a2+1][p]}. grid (2 p-tiles, 2 a-tiles, 64 b) x 256.
__global__ __launch_bounds__(256) void k_att1(
        const float* __restrict__ enc, const float* __restrict__ Wea,
        unsigned int* __restrict__ att1h) {
    int n0 = blockIdx.x * 128;   // p tile
    int m0 = blockIdx.y * 128;   // a tile
    int b  = blockIdx.z;
    __shared__ __align__(16) unsigned short At[128][40];  // [a][k] fp16
    __shared__ __align__(16) unsigned short Bt[128][40];  // [p][k] fp16
    int tid = threadIdx.x;
    int lane = tid & 63, w = tid >> 6;
    int wm = (w & 1) * 64, wn = (w >> 1) * 64;
    f32x4 acc[4][4];
#pragma unroll
    for (int i = 0; i < 4; i++)
#pragma unroll
        for (int j = 0; j < 4; j++) acc[i][j] = (f32x4){0.f, 0.f, 0.f, 0.f};

    for (int k0 = 0; k0 < ENC_; k0 += 32) {
#pragma unroll
        for (int l = 0; l < 2; l++) {
            int idx = l * 256 + tid;          // 0..511
            int r = idx >> 2, kc = (idx & 3) * 8;
            // A: Wea row a = m0 + r (always < 256)
            const float* ap = Wea + (size_t)(m0 + r) * ENC_ + k0 + kc;
            float4 f0 = *reinterpret_cast<const float4*>(ap);
            float4 f1 = *reinterpret_cast<const float4*>(ap + 4);
            uint4 av;
            av.x = pkh2(f0.x, f0.y); av.y = pkh2(f0.z, f0.w);
            av.z = pkh2(f1.x, f1.y); av.w = pkh2(f1.z, f1.w);
            *reinterpret_cast<uint4*>(&At[r][kc]) = av;
            // B: enc row p = n0 + r
            uint4 bv = make_uint4(0u, 0u, 0u, 0u);
            int p = n0 + r;
            if (p < P_) {
                const float* bp = enc + ((size_t)b * P_ + p) * ENC_ + k0 + kc;
                float4 g0 = *reinterpret_cast<const float4*>(bp);
                float4 g1 = *reinterpret_cast<const float4*>(bp + 4);
                bv.x = pkh2(g0.x, g0.y); bv.y = pkh2(g0.z, g0.w);
                bv.z = pkh2(g1.x, g1.y); bv.w = pkh2(g1.z, g1.w);
            }
            *reinterpret_cast<uint4*>(&Bt[r][kc]) = bv;
        }
        __syncthreads();
        int qk = (lane >> 4) * 8, fr = lane & 15;
        half8 a[4], bb[4];
#pragma unroll
        for (int i = 0; i < 4; i++) {
            a[i]  = *reinterpret_cast<const half8*>(&At[wm + i * 16 + fr][qk]);
            bb[i] = *reinterpret_cast<const half8*>(&Bt[wn + i * 16 + fr][qk]);
        }
#pragma unroll
        for (int i = 0; i < 4; i++)
#pragma unroll
            for (int j = 0; j < 4; j++)
                acc[i][j] = __builtin_amdgcn_mfma_f32_16x16x32_f16(a[i], bb[j], acc[i][j], 0, 0, 0);
        __syncthreads();
    }
    unsigned int* eb = att1h + (size_t)b * A1N_;
    int col = lane & 15, qr = (lane >> 4) * 4;
#pragma unroll
    for (int j = 0; j < 4; j++) {
        int p = n0 + wn + j * 16 + col;
        if (p < 208) {
#pragma unroll
            for (int i = 0; i < 4; i++) {
                int a0r = m0 + wm + i * 16 + qr;   // even
                eb[(size_t)(a0r >> 1) * 208 + p]       = pkh2(acc[i][j][0], acc[i][j][1]);
                eb[(size_t)((a0r >> 1) + 1) * 208 + p] = pkh2(acc[i][j][2], acc[i][j][3]);
            }
        }
    }
}

// ---------- embW[(t*64+b)][j] = b_ih[j]+b_hh[j] + sum_e emb[cap(b,t)][e]*W_ih[j][512+e] ----------
__global__ __launch_bounds__(256) void k_embW(
        const int* __restrict__ caption, const float* __restrict__ embedding,
        const float* __restrict__ WiheT, const float* __restrict__ b_ih,
        const float* __restrict__ b_hh, float* __restrict__ embW) {
    int r0 = blockIdx.x * 16, tid = threadIdx.x;
    __shared__ float embL[16][256];
    __shared__ int capL[16];
    if (tid < 16) {
        int r = r0 + tid, t = r >> 6, b = r & 63;
        capL[tid] = caption[b * T_ + t];
    }
    __syncthreads();
#pragma unroll
    for (int lr = 0; lr < 16; lr++)
        embL[lr][tid] = embedding[(size_t)capL[lr] * EMB_ + tid];
    __syncthreads();
    float base0 = b_ih[tid] + b_hh[tid];
    float base1 = b_ih[tid + 256] + b_hh[tid + 256];
    float base2 = b_ih[tid + 512] + b_hh[tid + 512];
    float base3 = b_ih[tid + 768] + b_hh[tid + 768];
    float acc[16][4];
#pragma unroll
    for (int lr = 0; lr < 16; lr++) {
        acc[lr][0] = base0; acc[lr][1] = base1; acc[lr][2] = base2; acc[lr][3] = base3;
    }
    for (int e = 0; e < EMB_; e++) {
        const float* wr = WiheT + (size_t)e * G4_ + tid;
        float w0 = wr[0], w1 = wr[256], w2 = wr[512], w3 = wr[768];
#pragma unroll
        for (int lr = 0; lr < 16; lr++) {
            float ev = embL[lr][e];
            acc[lr][0] += w0 * ev; acc[lr][1] += w1 * ev;
            acc[lr][2] += w2 * ev; acc[lr][3] += w3 * ev;
        }
    }
#pragma unroll
    for (int lr = 0; lr < 16; lr++) {
        float* o = embW + (size_t)(r0 + lr) * G4_ + tid;
        o[0] = acc[lr][0]; o[256] = acc[lr][1]; o[512] = acc[lr][2]; o[768] = acc[lr][3];
    }
}

// ---------- the sequential recurrence: TWO blocks per batch element (grid 128) ----------
// Blocks 2b (half A) and 2b+1 (half B) cooperate on b. P1/P2/softmax/P5 REPLICATED
// (bit-identical: a+b==b+a); P3/P4 SPLIT by consumer k-range:
//   A: gate k2 in [0,192)   <-> ctx e in [0,384)
//   B: gate k2 in [192,384) <-> ctx e in [384,512) (+h via replicated P5)
// Exchange protocol (race-free): gpart double-buffered by step parity, so the partner
// may lag a full step without clobber; per-block MONOTONIC sequence flags -- each block
// only WRITES its own flag (release) and READS the partner's (acquire). Flags zeroed by
// k_zeroflags before each k_recur in-stream. Deadlock-free: 128 blocks x 140.8KB LDS =
// 1 block/CU on 256 CUs -> all co-resident; partner always makes progress.
__global__ __launch_bounds__(1024, 4) void k_recur(
        const unsigned int* __restrict__ att1h, const float4* __restrict__ WdaP4,
        const float* __restrict__ W_full, const float4* __restrict__ Wg4,
        const float* __restrict__ embW, const uint2* __restrict__ encPh,
        const float* __restrict__ h0, const float* __restrict__ c0,
        float* __restrict__ gpart, unsigned int* __restrict__ gflag,
        unsigned short* __restrict__ Hbf, float* __restrict__ out_alpha) {
    int blk = blockIdx.x, tid = threadIdx.x;
    int pair = blk >> 1, half = blk & 1, b = pair;
    int q = tid >> 8;        // 0..3 k-split group
    int r = tid & 255;

    __shared__ __align__(16) float h_l[DEC_];
    __shared__ __align__(16) float att2_l[ATT_];
    __shared__ __align__(16) float wf_l[ATT_];
    __shared__ __align__(16) _Float16 xh[XW_];     // [ctx fp16(512); h fp16(256)]
    __shared__ __align__(8)  _Float16 alpha_h[208];
    __shared__ float p1[4][256];
    __shared__ float p2[4][256];
    __shared__ float p3[2][512];
    __shared__ __align__(16) float4 p4s[4][256];
    // att1 fp16, resident for the whole kernel. +48 pad: P2 reads index up to 127*208+255.
    __shared__ unsigned int att1_lds[A1N_ + 48];

    // ---- stage att1 into LDS (once) + init state (both halves identical)
    {
        const unsigned int* a1g = att1h + (size_t)b * A1N_;
        for (int i = tid; i < A1N_; i += 1024) att1_lds[i] = a1g[i];
    }
    if (tid < 256) {
        float hv = h0[b * DEC_ + tid];
        h_l[tid] = hv;
        xh[512 + tid] = (_Float16)hv;
        wf_l[tid] = W_full[tid];
    }
    float c = (tid < 256) ? c0[b * DEC_ + tid] : 0.f;
    __syncthreads();

    const uint2* encb = encPh + (size_t)b * (49 * ENC_);

    for (int t = 0; t < T_; ++t) {
        int par = t & 1;
        float* gme = gpart + ((size_t)blk * 2 + par) * G4_;           // my partial (this parity)
        const float* gpt = gpart + ((size_t)(blk ^ 1) * 2 + par) * G4_;  // partner partial

        // ---- P1 (replicated): att2 partial over d in [q*64,(q+1)*64), thread r = a
        float a2 = 0.f;
#pragma unroll 4
        for (int i = 0; i < 16; i++) {
            int d4 = q * 16 + i;
            float4 w = WdaP4[(size_t)d4 * 256 + r];
            float4 h4 = *reinterpret_cast<const float4*>(&h_l[4 * d4]);
            a2 += w.x * h4.x + w.y * h4.y + w.z * h4.z + w.w * h4.w;
        }
        p1[q][r] = a2;
        bar();
        if (tid < 256) att2_l[tid] = p1[0][tid] + p1[1][tid] + p1[2][tid] + p1[3][tid];
        bar();

        // ---- P2 (replicated): score partial over a-pairs in [q*32,(q+1)*32), LDS att1
        float sp = 0.f;
#pragma unroll 4
        for (int i = 0; i < 32; i++) {
            int a2i = q * 32 + i;
            f16x2 av = __builtin_bit_cast(f16x2, att1_lds[a2i * 208 + r]);
            float2 t2 = *reinterpret_cast<const float2*>(&att2_l[2 * a2i]);
            float2 w4 = *reinterpret_cast<const float2*>(&wf_l[2 * a2i]);
            sp += fmaxf((float)av.x + t2.x, 0.f) * w4.x +
                  fmaxf((float)av.y + t2.y, 0.f) * w4.y;
        }
        p2[q][r] = sp;
        bar();

        // ---- fused softmax (replicated; no max-subtraction, fp32 exp safe)
        float sden = 0.f;
        {
            int l = tid & 63;
#pragma unroll
            for (int cq = 0; cq < 4; cq++) {
                int cc = l + cq * 64;
                float s = p2[0][cc] + p2[1][cc] + p2[2][cc] + p2[3][cc];
                sden += (cc < P_) ? __expf(s) : 0.f;
            }
#pragma unroll
            for (int off = 32; off; off >>= 1) sden += __shfl_xor(sden, off);
        }
        if (tid < 256) {
            float s = p2[0][tid] + p2[1][tid] + p2[2][tid] + p2[3][tid];
            float ex = (tid < P_) ? __expf(s) : 0.f;
            float alpha = ex / sden;         // == 0 for tid >= P_
            if (tid < 208) alpha_h[tid] = (_Float16)alpha;
            if (half == 0 && tid < P_)
                out_alpha[(size_t)b * (T_ * P_) + t * P_ + tid] = alpha;
        }
        bar();

        // ---- P3 (split by consumer e-range): thread computes ctx[e] for its half's e's
        if (half == 0) {
            if (tid < 768) {
                int php = (tid >= 384) ? 1 : 0;
                int e2 = tid - php * 384;          // 0..383
                int p4b2 = php ? 25 : 0, p4e2 = php ? 49 : 25;
                float cx = 0.f;
                for (int p4 = p4b2; p4 < p4e2; p4++) {
                    uint2 ev = encb[(size_t)p4 * ENC_ + e2];
                    f16x2 a01 = *reinterpret_cast<const f16x2*>(&alpha_h[4 * p4]);
                    f16x2 a23 = *reinterpret_cast<const f16x2*>(&alpha_h[4 * p4 + 2]);
                    cx = fdot2u(ev.x, a01, cx);
                    cx = fdot2u(ev.y, a23, cx);
                }
                p3[php][e2] = cx;
            }
        } else {
            if (tid < 256) {
                int php = tid >> 7;
                int e2 = 384 + (tid & 127);        // 384..511
                int p4b2 = php ? 25 : 0, p4e2 = php ? 49 : 25;
                float cx = 0.f;
                for (int p4 = p4b2; p4 < p4e2; p4++) {
                    uint2 ev = encb[(size_t)p4 * ENC_ + e2];
                    f16x2 a01 = *reinterpret_cast<const f16x2*>(&alpha_h[4 * p4]);
                    f16x2 a23 = *reinterpret_cast<const f16x2*>(&alpha_h[4 * p4 + 2]);
                    cx = fdot2u(ev.x, a01, cx);
                    cx = fdot2u(ev.y, a23, cx);
                }
                p3[php][e2] = cx;
            }
        }
        // embW row prefetch (replicated; 4 VGPRs held across P4)
        float ew0 = 0.f, ew1 = 0.f, ew2 = 0.f, ew3 = 0.f;
        if (tid < 256) {
            const float* ew = embW + ((size_t)t * B_ + b) * G4_;
            ew0 = ew[tid]; ew1 = ew[tid + 256]; ew2 = ew[tid + 512]; ew3 = ew[tid + 768];
        }
        bar();
        if (half == 0) {
            if (tid < 384) xh[tid] = (_Float16)(p3[0][tid] + p3[1][tid]);
        } else {
            if (tid < 128) xh[384 + tid] = (_Float16)(p3[0][384 + tid] + p3[1][384 + tid]);
        }
        bar();

        // ---- P4 (split): k2 in [half*192 + q*48, +48), fp16 weights, thread r = d
        float4 acc = {0.f, 0.f, 0.f, 0.f};
        int kb = half * 192 + q * 48;
#pragma unroll 8
        for (int i = 0; i < 48; i++) {
            int k2 = kb + i;
            float4 w = Wg4[(size_t)k2 * 256 + r];
            f16x2 xv = *reinterpret_cast<const f16x2*>(&xh[2 * k2]);
            acc.x = fdot2f(w.x, xv, acc.x);
            acc.y = fdot2f(w.y, xv, acc.y);
            acc.z = fdot2f(w.z, xv, acc.z);
            acc.w = fdot2f(w.w, xv, acc.w);
        }
        p4s[q][r] = acc;
        __syncthreads();

        // ---- exchange: my half-gate partial -> gpart (parity buffer), then flag handshake
        float4 own = {0.f, 0.f, 0.f, 0.f};
        if (tid < 256) {
            float4 g0 = p4s[0][tid], g1 = p4s[1][tid], g2 = p4s[2][tid], g3 = p4s[3][tid];
            own.x = g0.x + g1.x + g2.x + g3.x;
            own.y = g0.y + g1.y + g2.y + g3.y;
            own.z = g0.z + g1.z + g2.z + g3.z;
            own.w = g0.w + g1.w + g2.w + g3.w;
            __hip_atomic_store(&gme[tid],       own.x, __ATOMIC_RELAXED, __HIP_MEMORY_SCOPE_AGENT);
            __hip_atomic_store(&gme[tid + 256], own.y, __ATOMIC_RELAXED, __HIP_MEMORY_SCOPE_AGENT);
            __hip_atomic_store(&gme[tid + 512], own.z, __ATOMIC_RELAXED, __HIP_MEMORY_SCOPE_AGENT);
            __hip_atomic_store(&gme[tid + 768], own.w, __ATOMIC_RELAXED, __HIP_MEMORY_SCOPE_AGENT);
        }
        __syncthreads();   // all lanes' data stores issued & retired (vmcnt drained)
        if (tid == 0) {
            // publish my step (release orders the data stores before the flag)
            __hip_atomic_store(&gflag[blk], (unsigned int)(t + 1),
                               __ATOMIC_RELEASE, __HIP_MEMORY_SCOPE_AGENT);
            // wait for partner's step (acquire orders subsequent partial loads)
            while (__hip_atomic_load(&gflag[blk ^ 1], __ATOMIC_ACQUIRE,
                                     __HIP_MEMORY_SCOPE_AGENT) < (unsigned int)(t + 1))
                __builtin_amdgcn_s_sleep(2);
        }
        __syncthreads();

        // ---- P5 (replicated): full gates = own + partner + embW; LSTM pointwise
        if (tid < 256) {
            float px = __hip_atomic_load(&gpt[tid],       __ATOMIC_RELAXED, __HIP_MEMORY_SCOPE_AGENT);
            float py = __hip_atomic_load(&gpt[tid + 256], __ATOMIC_RELAXED, __HIP_MEMORY_SCOPE_AGENT);
            float pz = __hip_atomic_load(&gpt[tid + 512], __ATOMIC_RELAXED, __HIP_MEMORY_SCOPE_AGENT);
            float pw = __hip_atomic_load(&gpt[tid + 768], __ATOMIC_RELAXED, __HIP_MEMORY_SCOPE_AGENT);
            float gi = (own.x + px) + ew0;   // a+b bitwise == b+a: both halves identical
            float gf = (own.y + py) + ew1;
            float gg = (own.z + pz) + ew2;
            float go = (own.w + pw) + ew3;
            float i_g = 1.f / (1.f + __expf(-gi));
            float f_g = 1.f / (1.f + __expf(-gf));
            float g_g = tanhf(gg);
            float o_g = 1.f / (1.f + __expf(-go));
            c = f_g * c + i_g * g_g;
            float hn = o_g * tanhf(c);
            h_l[tid] = hn;
            xh[512 + tid] = (_Float16)hn;
            if (half == 0)
                Hbf[((size_t)t * B_ + b) * DEC_ + tid] = f2bf(hn);
        }
        bar();
    }
}

// ---------- logits: C[m][n] = H[m,:] . Wout[n,:] + b_out[n], bf16 MFMA ----------
__global__ __launch_bounds__(256) void k_logits(
        const unsigned short* __restrict__ Hbf, const unsigned short* __restrict__ Woutbf,
        const float* __restrict__ b_out, float* __restrict__ out) {
    int n0 = blockIdx.x * 128, m0 = blockIdx.y * 128;
    __shared__ __align__(16) unsigned short At[128][40];
    __shared__ __align__(16) unsigned short Bt[128][40];
    int tid = threadIdx.x;
    int lane = tid & 63, w = tid >> 6;
    int wm = (w & 1) * 64, wn = (w >> 1) * 64;
    f32x4 acc[4][4];
#pragma unroll
    for (int i = 0; i < 4; i++)
#pragma unroll
        for (int j = 0; j < 4; j++) acc[i][j] = (f32x4){0.f, 0.f, 0.f, 0.f};

    for (int k0 = 0; k0 < DEC_; k0 += 32) {
#pragma unroll
        for (int l = 0; l < 2; l++) {
            int idx = l * 256 + tid;         // 0..511
            int r = idx >> 2, kc = (idx & 3) * 8;
            uint4 av = *reinterpret_cast<const uint4*>(&Hbf[(size_t)(m0 + r) * DEC_ + k0 + kc]);
            *reinterpret_cast<uint4*>(&At[r][kc]) = av;
            uint4 bv = make_uint4(0u, 0u, 0u, 0u);
            if (n0 + r < V_)
                bv = *reinterpret_cast<const uint4*>(&Woutbf[(size_t)(n0 + r) * DEC_ + k0 + kc]);
            *reinterpret_cast<uint4*>(&Bt[r][kc]) = bv;
        }
        __syncthreads();
        int qk = (lane >> 4) * 8, fr = lane & 15;
        short8 a[4], bb[4];
#pragma unroll
        for (int i = 0; i < 4; i++) {
            a[i]  = *reinterpret_cast<const short8*>(&At[wm + i * 16 + fr][qk]);
            bb[i] = *reinterpret_cast<const short8*>(&Bt[wn + i * 16 + fr][qk]);
        }
#pragma unroll
        for (int i = 0; i < 4; i++)
#pragma unroll
            for (int j = 0; j < 4; j++)
                acc[i][j] = __builtin_amdgcn_mfma_f32_16x16x32_bf16(a[i], bb[j], acc[i][j], 0, 0, 0);
        __syncthreads();
    }
    int col = lane & 15, qr = (lane >> 4) * 4;
#pragma unroll
    for (int j = 0; j < 4; j++) {
        int n = n0 + wn + j * 16 + col;
        if (n < V_) {
            float bo = b_out[n];
#pragma unroll
            for (int i = 0; i < 4; i++)
#pragma unroll
                for (int rr = 0; rr < 4; rr++) {
                    int m = m0 + wm + i * 16 + qr + rr;
                    int t = m >> 6, bb2 = m & 63;
                    out[(size_t)bb2 * (T_ * V_) + (size_t)t * V_ + n] = acc[i][j][rr] + bo;
                }
        }
    }
}

// ---------- launch ----------
extern "C" void kernel_launch(void* const* d_in, const int* in_sizes, int n_in,
                              void* d_out, int out_size, void* d_ws, size_t ws_size,
                              hipStream_t stream) {
    const float* enc       = (const float*)d_in[0];
    const int*   caption   = (const int*)d_in[1];
    const float* W_enc_att = (const float*)d_in[2];
    const float* W_dec_att = (const float*)d_in[3];
    const float* W_full    = (const float*)d_in[4];
    const float* embedding = (const float*)d_in[5];
    const float* W_init_h  = (const float*)d_in[6];
    const float* b_init_h  = (const float*)d_in[7];
    const float* W_init_c  = (const float*)d_in[8];
    const float* b_init_c  = (const float*)d_in[9];
    const float* W_ih      = (const float*)d_in[10];
    const float* b_ih      = (const float*)d_in[11];
    const float* W_hh      = (const float*)d_in[12];
    const float* b_hh      = (const float*)d_in[13];
    const float* W_out     = (const float*)d_in[14];
    const float* b_out     = (const float*)d_in[15];

    float* ws = (float*)d_ws;
    float* h0    = ws;                    //      16384
    float* c0    = ws + 16384;            //      16384
    float* WdaP  = ws + 32768;            //      65536  [64 d4][256 a] float4
    float* WiheT = ws + 98304;            //     262144  [256 e][1024 j]
    float* Wg4   = ws + 360448;           //     393216  [384 k2][256 d] 4x half2
    float* embW  = ws + 753664;           //    2883584  [t*64+b][1024]
    float* att1h = ws + 3637248;          //    1703936  [b][128 a2][208 p] f16x2 (u32)
    float* encPh = ws + 5341184;          //    3211264  [b][49 p4][512 e] uint2 fp16
    unsigned short* Hbf    = (unsigned short*)(ws + 8552448);   // 2816*256 bf16 = 360448 fl
    unsigned short* Woutbf = (unsigned short*)(ws + 8912896);   // 10000*256 bf16 = 1280000 fl
    float* gpart = ws + 10192896;         //     262144  [128 blk][2 par][1024 j]
    unsigned int* gflag = (unsigned int*)(ws + 10455040);       // 128 per-block step flags
    // total: 10455168 floats ~= 41.8 MB

    float* out_pred  = (float*)d_out;
    float* out_alpha = out_pred + (size_t)B_ * T_ * V_;

    k_transpose<<<dim3(8, 32), 256, 0, stream>>>(W_ih, WiheT, G4_, XW_, ENC_);
    k_packWda<<<64, 256, 0, stream>>>(W_dec_att, (float4*)WdaP);
    k_packWg<<<384, 256, 0, stream>>>(W_ih, W_hh, (float4*)Wg4);
    k_packenc<<<dim3(64, 7), 256, 0, stream>>>(enc, (uint2*)encPh);
    k_cvt<<<10000, 256, 0, stream>>>(W_out, Woutbf, V_ * DEC_);
    k_zeroflags<<<1, 128, 0, stream>>>(gflag);
    k_init_state<<<B_, 256, 0, stream>>>(enc, W_init_h, b_init_h, W_init_c, b_init_c, h0, c0);
    k_att1<<<dim3(2, 2, 64), 256, 0, stream>>>(enc, W_enc_att, (unsigned int*)att1h);
    k_embW<<<176, 256, 0, stream>>>(caption, embedding, WiheT, b_ih, b_hh, embW);
    k_recur<<<128, 1024, 0, stream>>>((const unsigned int*)att1h, (const float4*)WdaP, W_full,
                                      (const float4*)Wg4, embW, (const uint2*)encPh,
                                      h0, c0, gpart, gflag, Hbf, out_alpha);
    k_logits<<<dim3(79, 22), 256, 0, stream>>>(Hbf, Woutbf, b_out, out_pred);
}